// Round 5
// baseline (3700.270 us; speedup 1.0000x reference)
//
#include <hip/hip_runtime.h>
#include <hip/hip_bf16.h>

typedef __attribute__((ext_vector_type(8))) short short8;
typedef __attribute__((ext_vector_type(4))) float f32x4;

#define NROWS 38400      // B*L = 8*4800
#define LSEQ 4800
#define BATCH 8
#define NHEAD 8
#define QKV_LD 768

__device__ inline float b2f(ushort u) {
  union { ushort s; __hip_bfloat16 h; } c;
  c.s = u;
  return __bfloat162float(c.h);
}
__device__ inline ushort f2b(float f) {
  union { ushort s; __hip_bfloat16 h; } c;
  c.h = __float2bfloat16(f);
  return c.s;
}

// async global->LDS, 16B per lane. LDS dst = wave-uniform base + lane*16.
__device__ inline void gll16(const void* g, void* l) {
  __builtin_amdgcn_global_load_lds(
      (const __attribute__((address_space(1))) void*)g,
      (__attribute__((address_space(3))) void*)l, 16, 0, 0);
}

// ---------------------------------------------------------------------------
// Tiled transpose + fp32->bf16: dst[c][r] = src[r][c], batched over blockIdx.z.
// ---------------------------------------------------------------------------
__global__ __launch_bounds__(256) void transpose_bf16(
    const float* __restrict__ src, __hip_bfloat16* __restrict__ dst, int R, int C) {
  src += (size_t)blockIdx.z * R * C;
  dst += (size_t)blockIdx.z * R * C;
  __shared__ float tile[32][33];
  int bx = blockIdx.x, by = blockIdx.y;
  int tx = threadIdx.x & 31, ty = threadIdx.x >> 5;
  for (int rr = ty; rr < 32; rr += 8)
    tile[rr][tx] = src[(long)(by * 32 + rr) * C + bx * 32 + tx];
  __syncthreads();
  for (int rr = ty; rr < 32; rr += 8)
    dst[(long)(bx * 32 + rr) * R + by * 32 + tx] = __float2bfloat16(tile[tx][rr]);
}

// ---------------------------------------------------------------------------
// Init (float4-vectorized): residual stream + bf16 mirrors.
// ---------------------------------------------------------------------------
__global__ __launch_bounds__(256) void init_x(
    const float* __restrict__ d0, const float* __restrict__ d1,
    float* __restrict__ outF, __hip_bfloat16* __restrict__ X0b,
    __hip_bfloat16* __restrict__ X1b, long n4) {
  long i = (long)blockIdx.x * 256 + threadIdx.x;
  if (i < n4) {
    float4 a = ((const float4*)d0)[i];
    float4 b = ((const float4*)d1)[i];
    ((float4*)outF)[i] = a;
    ((float4*)outF)[n4 + i] = b;
    ushort4 ua = {f2b(a.x), f2b(a.y), f2b(a.z), f2b(a.w)};
    ushort4 ub = {f2b(b.x), f2b(b.y), f2b(b.z), f2b(b.w)};
    ((ushort4*)X0b)[i] = ua;
    ((ushort4*)X1b)[i] = ub;
  }
}

// ---------------------------------------------------------------------------
// Fused QKV projection GEMM. BM=128, BN=128, K=256, ldA=256, ldC=768.
// ---------------------------------------------------------------------------
__global__ __launch_bounds__(256) void gemm_qkv(
    const __hip_bfloat16* __restrict__ A, const __hip_bfloat16* __restrict__ Bt,
    __hip_bfloat16* __restrict__ C, int col0,
    const float* __restrict__ bq, const float* __restrict__ bk,
    const float* __restrict__ bv, const float* __restrict__ mq,
    const float* __restrict__ mkv) {
  __shared__ alignas(16) char smem[128 * 136 * 2];
  __hip_bfloat16 (*As)[64] = (__hip_bfloat16(*)[64])smem;
  __hip_bfloat16 (*Bs)[64] = (__hip_bfloat16(*)[64])(smem + 128 * 64 * 2);
  ushort (*Cs)[136] = (ushort(*)[136])smem;

  int tid = threadIdx.x;
  int wave = tid >> 6, lane = tid & 63;
  int wm = wave & 1, wn = wave >> 1;
  int quad = lane >> 4, l16 = lane & 15;
  long mbase = (long)blockIdx.y * 128;
  int nbase = blockIdx.x * 128;

  int srow = lane >> 3;
  int sck = (lane & 7) ^ srow;
  int cx = l16 & 7;

  f32x4 acc[4][4];
#pragma unroll
  for (int i = 0; i < 4; i++)
#pragma unroll
    for (int j = 0; j < 4; j++) acc[i][j] = (f32x4){0.f, 0.f, 0.f, 0.f};

  for (int kt = 0; kt < 256; kt += 64) {
    __syncthreads();
#pragma unroll
    for (int i = 0; i < 4; i++) {
      int r0 = wave * 32 + i * 8;
      gll16(A + (mbase + r0 + srow) * 256 + kt + sck * 8, &As[r0][0]);
      gll16(Bt + (long)(nbase + r0 + srow) * 256 + kt + sck * 8, &Bs[r0][0]);
    }
    __syncthreads();
#pragma unroll
    for (int ks = 0; ks < 64; ks += 32) {
      short8 af[4], bfr[4];
      int ch = ((ks >> 3) + quad) ^ cx;
#pragma unroll
      for (int mt = 0; mt < 4; mt++)
        af[mt] = *(const short8*)&As[wm * 64 + mt * 16 + l16][ch * 8];
#pragma unroll
      for (int nt = 0; nt < 4; nt++)
        bfr[nt] = *(const short8*)&Bs[wn * 64 + nt * 16 + l16][ch * 8];
#pragma unroll
      for (int mt = 0; mt < 4; mt++)
#pragma unroll
        for (int nt = 0; nt < 4; nt++)
          acc[mt][nt] = __builtin_amdgcn_mfma_f32_16x16x32_bf16(
              af[mt], bfr[nt], acc[mt][nt], 0, 0, 0);
    }
  }

  __syncthreads();
  int gc0 = col0 + nbase;
#pragma unroll
  for (int nt = 0; nt < 4; nt++) {
    int colt = wn * 64 + nt * 16 + l16;
    int gcol = gc0 + colt;
    int seg = gcol >> 8;
    int ci = gcol & 255;
    float bvv = (seg == 0) ? bq[ci] : (seg == 1) ? bk[ci] : bv[ci];
    const float* mask = (seg == 0) ? mq : mkv;
    bool doelu = seg < 2;
#pragma unroll
    for (int mt = 0; mt < 4; mt++) {
      int rowt0 = wm * 64 + mt * 16 + quad * 4;
#pragma unroll
      for (int r = 0; r < 4; r++) {
        int rowt = rowt0 + r;
        float v = acc[mt][nt][r] + bvv;
        if (doelu) v = v > 0.f ? v + 1.f : __expf(v);
        v *= mask[mbase + rowt];
        Cs[rowt][colt] = f2b(v);
      }
    }
  }
  __syncthreads();
#pragma unroll
  for (int it = 0; it < 8; it++) {
    int idx = tid + it * 256;
    int row = idx >> 4, c = idx & 15;
    uint4 v = *(const uint4*)&Cs[row][c * 8];
    *(uint4*)(C + (mbase + row) * (long)QKV_LD + gc0 + c * 8) = v;
  }
}

// ---------------------------------------------------------------------------
// FUSED TAIL v2: M = LN(Ab@WmT + bm) ; H1 = relu(M@w1T) ; O = H1@w2T ;
// out = LN(O)*g2+b2 + residual (fp32), Xb = bf16 mirror.
// 512 thr (8 waves), 64 rows/block. Weight B-fragments are PER-WAVE-EXCLUSIVE
// (wave w reads only rows w*32..w*32+31 of each weight panel) -> loaded
// DIRECTLY global->VGPR (L2/L1-hot), no LDS staging, no barrier pipeline.
// A-panel staged once (64x256, chunk-swizzled); M/H1 in LDS only.
// LDS 70144 B -> 2 blocks/CU; launch_bounds(512,4) pins VGPR<=128.
// ---------------------------------------------------------------------------
__global__ __launch_bounds__(512, 4) void tail_fused(
    const __hip_bfloat16* __restrict__ A, const __hip_bfloat16* __restrict__ WmT,
    const __hip_bfloat16* __restrict__ w1T, const __hip_bfloat16* __restrict__ w2T,
    const float* __restrict__ bm,
    const float* __restrict__ g1, const float* __restrict__ b1,
    const float* __restrict__ g2, const float* __restrict__ b2,
    float* __restrict__ outF, __hip_bfloat16* __restrict__ Xb) {
  __shared__ alignas(16) char smem[70144];
  ushort* AsH = (ushort*)smem;             // phase A: As[64][256]; later H1u
  ushort* Msu = (ushort*)(smem + 32768);   // M [64][256] swizzled; later Xsu
  float* pS  = (float*)(smem + 65536);     // [8][64]
  float* pS2 = (float*)(smem + 67584);     // [8][64]
  float* muA = (float*)(smem + 69632);     // [64]
  float* rsA = (float*)(smem + 69888);     // [64]

  int tid = threadIdx.x;
  int wave = tid >> 6, lane = tid & 63;
  int quad = lane >> 4, l16 = lane & 15;
  long mbase = (long)blockIdx.x * 64;
  int cx = l16 & 7;            // == (fragment row)&7 for rows mt*16+l16
  int rswL = cx * 8;           // Msu/H1u column XOR for this lane's rows

  f32x4 accA[4][2], accC[4][2];
#pragma unroll
  for (int i = 0; i < 4; i++)
#pragma unroll
    for (int j = 0; j < 2; j++) {
      accA[i][j] = (f32x4){0.f, 0.f, 0.f, 0.f};
      accC[i][j] = (f32x4){0.f, 0.f, 0.f, 0.f};
    }

  // ---- stage full A-panel 64x256 (chunk-swizzled: LDS[r][j]=glob[r][j^(r&7)])
  {
    int r2 = lane >> 5;          // row within pair
    int c32 = lane & 31;         // chunk within row
#pragma unroll
    for (int j = 0; j < 4; j++) {
      int r0 = wave * 8 + j * 2;
      int r = r0 + r2;
      gll16(A + (mbase + r) * 256 + ((c32 ^ (r & 7)) * 8),
            (char*)AsH + r0 * 512);
    }
  }
  __syncthreads();   // drains vmcnt before barrier (HIP semantics)

  // ---- phase A: accA = Ab @ WmT (B-frags direct from global) ----
#pragma unroll
  for (int ks = 0; ks < 256; ks += 32) {
    short8 af[4], bfr[2];
#pragma unroll
    for (int nt = 0; nt < 2; nt++) {
      int n = wave * 32 + nt * 16 + l16;
      bfr[nt] = *(const short8*)&WmT[n * 256 + ks + quad * 8];
    }
    int ch = ((ks >> 3) + quad) ^ cx;
#pragma unroll
    for (int mt = 0; mt < 4; mt++)
      af[mt] = *(const short8*)&AsH[(mt * 16 + l16) * 256 + ch * 8];
#pragma unroll
    for (int mt = 0; mt < 4; mt++)
#pragma unroll
      for (int nt = 0; nt < 2; nt++)
        accA[mt][nt] = __builtin_amdgcn_mfma_f32_16x16x32_bf16(
            af[mt], bfr[nt], accA[mt][nt], 0, 0, 0);
  }

  // ---- LN1 -> Msu ----
  float br[2], gr[2], blr[2];
#pragma unroll
  for (int nt = 0; nt < 2; nt++) {
    int gcol = wave * 32 + nt * 16 + l16;
    br[nt] = bm[gcol];
    gr[nt] = g1[gcol];
    blr[nt] = b1[gcol];
  }
#pragma unroll
  for (int mt = 0; mt < 4; mt++)
#pragma unroll
    for (int r = 0; r < 4; r++) {
      float s = 0.f, s2 = 0.f;
#pragma unroll
      for (int nt = 0; nt < 2; nt++) {
        float v = accA[mt][nt][r] + br[nt];
        s += v;
        s2 += v * v;
      }
      s += __shfl_xor(s, 1);  s2 += __shfl_xor(s2, 1);
      s += __shfl_xor(s, 2);  s2 += __shfl_xor(s2, 2);
      s += __shfl_xor(s, 4);  s2 += __shfl_xor(s2, 4);
      s += __shfl_xor(s, 8);  s2 += __shfl_xor(s2, 8);
      if (l16 == 0) {
        int row = mt * 16 + quad * 4 + r;
        pS[wave * 64 + row] = s;
        pS2[wave * 64 + row] = s2;
      }
    }
  __syncthreads();
  if (tid < 64) {
    float S = 0.f, S2 = 0.f;
#pragma unroll
    for (int w = 0; w < 8; w++) { S += pS[w * 64 + tid]; S2 += pS2[w * 64 + tid]; }
    float mu = S * (1.f / 256.f);
    float var = S2 * (1.f / 256.f) - mu * mu;
    muA[tid] = mu;
    rsA[tid] = rsqrtf(var + 1e-5f);
  }
  __syncthreads();
#pragma unroll
  for (int mt = 0; mt < 4; mt++)
#pragma unroll
    for (int r = 0; r < 4; r++) {
      int row = mt * 16 + quad * 4 + r;
      float mu = muA[row], rs = rsA[row];
      int rsw = (row & 7) * 8;
#pragma unroll
      for (int nt = 0; nt < 2; nt++) {
        int col = wave * 32 + nt * 16 + l16;
        float v = accA[mt][nt][r] + br[nt];
        Msu[row * 256 + (col ^ rsw)] = f2b((v - mu) * rs * gr[nt] + blr[nt]);
      }
    }
  __syncthreads();   // Msu visible to all waves

  // ---- halves: B(half) -> H1 -> C(half), accC accumulates across halves ----
#pragma unroll
  for (int half = 0; half < 2; half++) {
    f32x4 accB[4][2];
#pragma unroll
    for (int i = 0; i < 4; i++)
#pragma unroll
      for (int j = 0; j < 2; j++) accB[i][j] = (f32x4){0.f, 0.f, 0.f, 0.f};
    const __hip_bfloat16* w1h = w1T + (size_t)half * 256 * 256;
#pragma unroll
    for (int ks = 0; ks < 256; ks += 32) {
      short8 af[4], bfr[2];
#pragma unroll
      for (int nt = 0; nt < 2; nt++) {
        int n = wave * 32 + nt * 16 + l16;
        bfr[nt] = *(const short8*)&w1h[n * 256 + ks + quad * 8];
      }
      int pcol = (ks + quad * 8) ^ rswL;
#pragma unroll
      for (int mt = 0; mt < 4; mt++)
        af[mt] = *(const short8*)&Msu[(mt * 16 + l16) * 256 + pcol];
#pragma unroll
      for (int mt = 0; mt < 4; mt++)
#pragma unroll
        for (int nt = 0; nt < 2; nt++)
          accB[mt][nt] = __builtin_amdgcn_mfma_f32_16x16x32_bf16(
              af[mt], bfr[nt], accB[mt][nt], 0, 0, 0);
    }
    __syncthreads();   // half0: AsH reads long done; half1: C(half0) done
#pragma unroll
    for (int mt = 0; mt < 4; mt++)
#pragma unroll
      for (int r = 0; r < 4; r++) {
        int row = mt * 16 + quad * 4 + r;
        int rsw = (row & 7) * 8;
#pragma unroll
        for (int nt = 0; nt < 2; nt++) {
          int col = wave * 32 + nt * 16 + l16;
          float v = accB[mt][nt][r];
          AsH[row * 256 + (col ^ rsw)] = f2b(v > 0.f ? v : 0.f);
        }
      }
    __syncthreads();   // H1 visible
#pragma unroll
    for (int ks = 0; ks < 256; ks += 32) {
      short8 af[4], bfr[2];
#pragma unroll
      for (int nt = 0; nt < 2; nt++) {
        int n = wave * 32 + nt * 16 + l16;
        bfr[nt] = *(const short8*)&w2T[n * 512 + half * 256 + ks + quad * 8];
      }
      int pcol = (ks + quad * 8) ^ rswL;
#pragma unroll
      for (int mt = 0; mt < 4; mt++)
        af[mt] = *(const short8*)&AsH[(mt * 16 + l16) * 256 + pcol];
#pragma unroll
      for (int mt = 0; mt < 4; mt++)
#pragma unroll
        for (int nt = 0; nt < 2; nt++)
          accC[mt][nt] = __builtin_amdgcn_mfma_f32_16x16x32_bf16(
              af[mt], bfr[nt], accC[mt][nt], 0, 0, 0);
    }
  }

  // ---- LN2 + residual + Xb ----
  float g2r[2], b2r[2];
#pragma unroll
  for (int nt = 0; nt < 2; nt++) {
    int gcol = wave * 32 + nt * 16 + l16;
    g2r[nt] = g2[gcol];
    b2r[nt] = b2[gcol];
  }
#pragma unroll
  for (int mt = 0; mt < 4; mt++)
#pragma unroll
    for (int r = 0; r < 4; r++) {
      float s = 0.f, s2 = 0.f;
#pragma unroll
      for (int nt = 0; nt < 2; nt++) {
        float v = accC[mt][nt][r];
        s += v;
        s2 += v * v;
      }
      s += __shfl_xor(s, 1);  s2 += __shfl_xor(s2, 1);
      s += __shfl_xor(s, 2);  s2 += __shfl_xor(s2, 2);
      s += __shfl_xor(s, 4);  s2 += __shfl_xor(s2, 4);
      s += __shfl_xor(s, 8);  s2 += __shfl_xor(s2, 8);
      if (l16 == 0) {
        int row = mt * 16 + quad * 4 + r;
        pS[wave * 64 + row] = s;
        pS2[wave * 64 + row] = s2;
      }
    }
  __syncthreads();
  if (tid < 64) {
    float S = 0.f, S2 = 0.f;
#pragma unroll
    for (int w = 0; w < 8; w++) { S += pS[w * 64 + tid]; S2 += pS2[w * 64 + tid]; }
    float mu = S * (1.f / 256.f);
    float var = S2 * (1.f / 256.f) - mu * mu;
    muA[tid] = mu;
    rsA[tid] = rsqrtf(var + 1e-5f);
  }
  __syncthreads();
  ushort* Xsu = Msu;   // Msu dead (last read: B half1) -> Xb staging
#pragma unroll
  for (int mt = 0; mt < 4; mt++)
#pragma unroll
    for (int r = 0; r < 4; r++) {
      int row = mt * 16 + quad * 4 + r;
      float mu = muA[row], rs = rsA[row];
      int qx = quad * 8;    // ((row>>2)&3)*8 == quad*8 here
#pragma unroll
      for (int nt = 0; nt < 2; nt++) {
        int gcol = wave * 32 + nt * 16 + l16;
        float ln = (accC[mt][nt][r] - mu) * rs * g2r[nt] + b2r[nt];
        float* op = outF + (mbase + row) * 256 + gcol;
        float rr = *op + ln;          // residual in fp32
        *op = rr;
        Xsu[row * 256 + (gcol ^ qx)] = f2b(rr);
      }
    }
  __syncthreads();
#pragma unroll
  for (int it = 0; it < 4; it++) {
    int idx = tid + it * 512;        // 0..2047 -> 64 rows x 32 chunks
    int row = idx >> 5, c = idx & 31;
    int pc = c ^ ((row >> 2) & 3);   // undo quad-XOR swizzle
    uint4 v = *(const uint4*)&Xsu[row * 256 + pc * 8];
    *(uint4*)(Xb + (mbase + row) * 256L + c * 8) = v;
  }
}

// ---------------------------------------------------------------------------
// KV reduce from QKV buffer (stride 768; K at +256, V at +512).
// ---------------------------------------------------------------------------
__global__ __launch_bounds__(256) void kv_reduce(
    const __hip_bfloat16* __restrict__ QKV, float* __restrict__ KV,
    float* __restrict__ Ksum) {
  int b = blockIdx.x, h = blockIdx.y, c = blockIdx.z;
  __shared__ float Kl[32][40], Vl[32][40];
  int t = threadIdx.x;
  int lrow = t >> 3, le = (t & 7) * 4;
  int d = t >> 3, mg = t & 7;
  float a0 = 0.f, a1 = 0.f, a2 = 0.f, a3 = 0.f, ks = 0.f;
  int base = c * 480;
  for (int st = 0; st < 15; st++) {
    int s0 = base + st * 32;
    __syncthreads();
    {
      long n = (long)b * LSEQ + s0 + lrow;
      ushort4 ku = *(const ushort4*)(QKV + n * QKV_LD + 256 + h * 32 + le);
      ushort4 vu = *(const ushort4*)(QKV + n * QKV_LD + 512 + h * 32 + le);
      float4 kf = {b2f(ku.x), b2f(ku.y), b2f(ku.z), b2f(ku.w)};
      float4 vf = {b2f(vu.x), b2f(vu.y), b2f(vu.z), b2f(vu.w)};
      *(float4*)&Kl[lrow][le] = kf;
      *(float4*)&Vl[lrow][le] = vf;
    }
    __syncthreads();
#pragma unroll
    for (int ss = 0; ss < 32; ss++) {
      float kd = Kl[ss][d];
      float4 v4 = *(const float4*)&Vl[ss][mg * 4];
      a0 += kd * v4.x; a1 += kd * v4.y; a2 += kd * v4.z; a3 += kd * v4.w;
      if (mg == 0) ks += kd;
    }
  }
  int bh = b * 8 + h;
  float* p = KV + ((long)bh * 32 + d) * 32 + mg * 4;
  atomicAdd(&p[0], a0); atomicAdd(&p[1], a1);
  atomicAdd(&p[2], a2); atomicAdd(&p[3], a3);
  if (mg == 0) atomicAdd(&Ksum[bh * 32 + d], ks);
}

// ---------------------------------------------------------------------------
// Attention output from QKV buffer (Q stride 768); writes O (stride 256).
// ---------------------------------------------------------------------------
__global__ __launch_bounds__(256) void attn_out(
    const __hip_bfloat16* __restrict__ QKV, const float* __restrict__ KV,
    const float* __restrict__ Ksum, __hip_bfloat16* __restrict__ O) {
  int b = blockIdx.y, h = blockIdx.z;
  int bh = b * 8 + h;
  __shared__ float KVl[32][36];
  int t = threadIdx.x;
  for (int i = t; i < 1024; i += 256) KVl[i >> 5][i & 31] = KV[((long)bh << 10) + i];
  int lane = t & 63, wave = t >> 6;
  int cg = lane & 7, rs = lane >> 3;
  float4 ksr = *(const float4*)&Ksum[bh * 32 + cg * 4];
  __syncthreads();

  int rowEnd = blockIdx.x * 192 + 192;
  for (int r = blockIdx.x * 192 + wave * 8 + rs; r < rowEnd; r += 32) {
    long n = (long)b * LSEQ + r;
    ushort4 qu = *(const ushort4*)(QKV + n * QKV_LD + h * 32 + cg * 4);
    float q0 = b2f(qu.x), q1 = b2f(qu.y), q2 = b2f(qu.z), q3 = b2f(qu.w);
    float den = q0 * ksr.x + q1 * ksr.y + q2 * ksr.z + q3 * ksr.w;
    den += __shfl_xor(den, 1);
    den += __shfl_xor(den, 2);
    den += __shfl_xor(den, 4);
    float s0 = 0.f, s1 = 0.f, s2 = 0.f, s3 = 0.f;
    int gbase = lane & ~7;
#pragma unroll
    for (int j = 0; j < 8; j++) {
      int src = gbase | j;
      float qa = __shfl(q0, src);
      float qb = __shfl(q1, src);
      float qc = __shfl(q2, src);
      float qd = __shfl(q3, src);
      float4 k0 = *(const float4*)&KVl[j * 4 + 0][cg * 4];
      float4 k1 = *(const float4*)&KVl[j * 4 + 1][cg * 4];
      float4 k2 = *(const float4*)&KVl[j * 4 + 2][cg * 4];
      float4 k3 = *(const float4*)&KVl[j * 4 + 3][cg * 4];
      s0 += qa * k0.x + qb * k1.x + qc * k2.x + qd * k3.x;
      s1 += qa * k0.y + qb * k1.y + qc * k2.y + qd * k3.y;
      s2 += qa * k0.z + qb * k1.z + qc * k2.z + qd * k3.z;
      s3 += qa * k0.w + qb * k1.w + qc * k2.w + qd * k3.w;
    }
    float inv = 1.0f / (den + 1e-6f);
    ushort4 ou = {f2b(s0 * inv), f2b(s1 * inv), f2b(s2 * inv), f2b(s3 * inv)};
    *(ushort4*)(O + n * 256 + h * 32 + cg * 4) = ou;
  }
}

// ---------------------------------------------------------------------------
extern "C" void kernel_launch(void* const* d_in, const int* in_sizes, int n_in,
                              void* d_out, int out_size, void* d_ws, size_t ws_size,
                              hipStream_t stream) {
  const float* desc0 = (const float*)d_in[0];
  const float* desc1 = (const float*)d_in[1];
  const float* mask0 = (const float*)d_in[2];
  const float* mask1 = (const float*)d_in[3];
  const float* Wq = (const float*)d_in[4];
  const float* bq = (const float*)d_in[5];
  const float* Wk = (const float*)d_in[6];
  const float* bk = (const float*)d_in[7];
  const float* Wv = (const float*)d_in[8];
  const float* bv = (const float*)d_in[9];
  const float* Wm = (const float*)d_in[10];
  const float* bm = (const float*)d_in[11];
  const float* w1 = (const float*)d_in[12];
  const float* w2 = (const float*)d_in[13];
  const float* g1 = (const float*)d_in[14];
  const float* b1 = (const float*)d_in[15];
  const float* g2 = (const float*)d_in[16];
  const float* b2 = (const float*)d_in[17];

  char* ws = (char*)d_ws;
  size_t used = 0;
  auto alloc = [&](size_t bytes) {
    char* p = ws + used;
    used += (bytes + 255) & ~(size_t)255;
    return p;
  };
  __hip_bfloat16* WqkvT = (__hip_bfloat16*)alloc((size_t)768 * 256 * 2);
  __hip_bfloat16* WmT = (__hip_bfloat16*)alloc(256 * 256 * 2);
  __hip_bfloat16* w1T = (__hip_bfloat16*)alloc((size_t)8 * 512 * 256 * 2);
  __hip_bfloat16* w2T = (__hip_bfloat16*)alloc((size_t)8 * 256 * 512 * 2);
  // X0b and X1b MUST stay adjacent: the merged path treats them as one
  // [2*NROWS,256] matrix.
  __hip_bfloat16* X0b = (__hip_bfloat16*)alloc((size_t)NROWS * 256 * 2);
  __hip_bfloat16* X1b = (__hip_bfloat16*)alloc((size_t)NROWS * 256 * 2);
  __hip_bfloat16* QKV = (__hip_bfloat16*)alloc((size_t)NROWS * QKV_LD * 2);
  __hip_bfloat16* Ab2 = (__hip_bfloat16*)alloc((size_t)2 * NROWS * 256 * 2);
  float* KVws = (float*)alloc((64 * 1024 + 64 * 32) * 4);
  float* Ksum = KVws + 64 * 1024;
  bool merged = used <= ws_size;

  // weight prep
  transpose_bf16<<<dim3(8, 8, 1), 256, 0, stream>>>(Wq, WqkvT, 256, 256);
  transpose_bf16<<<dim3(8, 8, 1), 256, 0, stream>>>(Wk, WqkvT + 65536, 256, 256);
  transpose_bf16<<<dim3(8, 8, 1), 256, 0, stream>>>(Wv, WqkvT + 131072, 256, 256);
  transpose_bf16<<<dim3(8, 8, 1), 256, 0, stream>>>(Wm, WmT, 256, 256);
  transpose_bf16<<<dim3(16, 8, 8), 256, 0, stream>>>(w1, w1T, 256, 512);
  transpose_bf16<<<dim3(8, 16, 8), 256, 0, stream>>>(w2, w2T, 512, 256);

  long nElem = (long)NROWS * 256;
  long n4 = nElem / 4;
  init_x<<<(n4 + 255) / 256, 256, 0, stream>>>(desc0, desc1, (float*)d_out,
                                               X0b, X1b, n4);

  // QKV projection + linear attention for one stream; output rows at Oout.
  auto attn_stage = [&](const __hip_bfloat16* Xq, const __hip_bfloat16* Xkv,
                        const float* mq, const float* ms,
                        __hip_bfloat16* Oout, bool self) {
    if (self) {
      gemm_qkv<<<dim3(6, 300), 256, 0, stream>>>(Xq, WqkvT, QKV, 0,
                                                 bq, bk, bv, mq, ms);
    } else {
      gemm_qkv<<<dim3(2, 300), 256, 0, stream>>>(Xq, WqkvT, QKV, 0,
                                                 bq, bk, bv, mq, ms);
      gemm_qkv<<<dim3(4, 300), 256, 0, stream>>>(Xkv, WqkvT + 65536, QKV, 256,
                                                 bq, bk, bv, mq, ms);
    }
    hipMemsetAsync(KVws, 0, (64 * 1024 + 64 * 32) * 4, stream);
    kv_reduce<<<dim3(BATCH, NHEAD, 10), 256, 0, stream>>>(QKV, KVws, Ksum);
    attn_out<<<dim3(25, BATCH, NHEAD), 256, 0, stream>>>(QKV, KVws, Ksum, Oout);
  };

  auto tail = [&](int nblk, int i, float* oF, __hip_bfloat16* Xb) {
    tail_fused<<<nblk, 512, 0, stream>>>(
        Ab2, WmT, w1T + (size_t)i * 512 * 256, w2T + (size_t)i * 256 * 512,
        bm, g1 + i * 256, b1 + i * 256, g2 + i * 256, b2 + i * 256, oF, Xb);
  };

  // Merged self pair: both streams' tails in one double-M launch.
  auto self_pair = [&](int i) {
    attn_stage(X0b, X0b, mask0, mask0, Ab2, true);
    attn_stage(X1b, X1b, mask1, mask1, Ab2 + nElem, true);
    tail(2 * NROWS / 64, i, (float*)d_out, X0b);
  };

  // Single-stream layer (cross layers, and fallback for self).
  auto layer_one = [&](int x, int s, int i) {
    __hip_bfloat16* Xx = x ? X1b : X0b;
    __hip_bfloat16* Xs = s ? X1b : X0b;
    const float* mx = x ? mask1 : mask0;
    const float* ms = s ? mask1 : mask0;
    attn_stage(Xx, Xs, mx, ms, Ab2, x == s);
    tail(NROWS / 64, i, (float*)d_out + (size_t)x * nElem, Xx);
  };

  for (int i = 0; i < 8; i++) {
    if (i % 2 == 0) {        // self: independent streams -> merge tails
      if (merged) {
        self_pair(i);
      } else {
        layer_one(0, 0, i);
        layer_one(1, 1, i);
      }
    } else {                 // cross (desc1 sees UPDATED desc0) -> sequential
      layer_one(0, 1, i);
      layer_one(1, 0, i);
    }
  }
}

// Round 6
// 3376.522 us; speedup vs baseline: 1.0959x; 1.0959x over previous
//
#include <hip/hip_runtime.h>
#include <hip/hip_bf16.h>

typedef __attribute__((ext_vector_type(8))) short short8;
typedef __attribute__((ext_vector_type(4))) float f32x4;

#define NROWS 38400      // B*L = 8*4800
#define LSEQ 4800
#define BATCH 8
#define NHEAD 8
#define QKV_LD 768

__device__ inline float b2f(ushort u) {
  union { ushort s; __hip_bfloat16 h; } c;
  c.s = u;
  return __bfloat162float(c.h);
}
__device__ inline ushort f2b(float f) {
  union { ushort s; __hip_bfloat16 h; } c;
  c.h = __float2bfloat16(f);
  return c.s;
}

// async global->LDS, 16B per lane. LDS dst = wave-uniform base + lane*16.
__device__ inline void gll16(const void* g, void* l) {
  __builtin_amdgcn_global_load_lds(
      (const __attribute__((address_space(1))) void*)g,
      (__attribute__((address_space(3))) void*)l, 16, 0, 0);
}

// ---------------------------------------------------------------------------
// Tiled transpose + fp32->bf16: dst[c][r] = src[r][c], batched over blockIdx.z.
// ---------------------------------------------------------------------------
__global__ __launch_bounds__(256) void transpose_bf16(
    const float* __restrict__ src, __hip_bfloat16* __restrict__ dst, int R, int C) {
  src += (size_t)blockIdx.z * R * C;
  dst += (size_t)blockIdx.z * R * C;
  __shared__ float tile[32][33];
  int bx = blockIdx.x, by = blockIdx.y;
  int tx = threadIdx.x & 31, ty = threadIdx.x >> 5;
  for (int rr = ty; rr < 32; rr += 8)
    tile[rr][tx] = src[(long)(by * 32 + rr) * C + bx * 32 + tx];
  __syncthreads();
  for (int rr = ty; rr < 32; rr += 8)
    dst[(long)(bx * 32 + rr) * R + by * 32 + tx] = __float2bfloat16(tile[tx][rr]);
}

// ---------------------------------------------------------------------------
// Init (float4-vectorized): residual stream + bf16 mirrors.
// ---------------------------------------------------------------------------
__global__ __launch_bounds__(256) void init_x(
    const float* __restrict__ d0, const float* __restrict__ d1,
    float* __restrict__ outF, __hip_bfloat16* __restrict__ X0b,
    __hip_bfloat16* __restrict__ X1b, long n4) {
  long i = (long)blockIdx.x * 256 + threadIdx.x;
  if (i < n4) {
    float4 a = ((const float4*)d0)[i];
    float4 b = ((const float4*)d1)[i];
    ((float4*)outF)[i] = a;
    ((float4*)outF)[n4 + i] = b;
    ushort4 ua = {f2b(a.x), f2b(a.y), f2b(a.z), f2b(a.w)};
    ushort4 ub = {f2b(b.x), f2b(b.y), f2b(b.z), f2b(b.w)};
    ((ushort4*)X0b)[i] = ua;
    ((ushort4*)X1b)[i] = ub;
  }
}

// ---------------------------------------------------------------------------
// Fused QKV projection GEMM. BM=128, BN=128, K=256, ldA=256, ldC=768.
// ---------------------------------------------------------------------------
__global__ __launch_bounds__(256) void gemm_qkv(
    const __hip_bfloat16* __restrict__ A, const __hip_bfloat16* __restrict__ Bt,
    __hip_bfloat16* __restrict__ C, int col0,
    const float* __restrict__ bq, const float* __restrict__ bk,
    const float* __restrict__ bv, const float* __restrict__ mq,
    const float* __restrict__ mkv) {
  __shared__ alignas(16) char smem[128 * 136 * 2];
  __hip_bfloat16 (*As)[64] = (__hip_bfloat16(*)[64])smem;
  __hip_bfloat16 (*Bs)[64] = (__hip_bfloat16(*)[64])(smem + 128 * 64 * 2);
  ushort (*Cs)[136] = (ushort(*)[136])smem;

  int tid = threadIdx.x;
  int wave = tid >> 6, lane = tid & 63;
  int wm = wave & 1, wn = wave >> 1;
  int quad = lane >> 4, l16 = lane & 15;
  long mbase = (long)blockIdx.y * 128;
  int nbase = blockIdx.x * 128;

  int srow = lane >> 3;
  int sck = (lane & 7) ^ srow;
  int cx = l16 & 7;

  f32x4 acc[4][4];
#pragma unroll
  for (int i = 0; i < 4; i++)
#pragma unroll
    for (int j = 0; j < 4; j++) acc[i][j] = (f32x4){0.f, 0.f, 0.f, 0.f};

  for (int kt = 0; kt < 256; kt += 64) {
    __syncthreads();
#pragma unroll
    for (int i = 0; i < 4; i++) {
      int r0 = wave * 32 + i * 8;
      gll16(A + (mbase + r0 + srow) * 256 + kt + sck * 8, &As[r0][0]);
      gll16(Bt + (long)(nbase + r0 + srow) * 256 + kt + sck * 8, &Bs[r0][0]);
    }
    __syncthreads();
#pragma unroll
    for (int ks = 0; ks < 64; ks += 32) {
      short8 af[4], bfr[4];
      int ch = ((ks >> 3) + quad) ^ cx;
#pragma unroll
      for (int mt = 0; mt < 4; mt++)
        af[mt] = *(const short8*)&As[wm * 64 + mt * 16 + l16][ch * 8];
#pragma unroll
      for (int nt = 0; nt < 4; nt++)
        bfr[nt] = *(const short8*)&Bs[wn * 64 + nt * 16 + l16][ch * 8];
#pragma unroll
      for (int mt = 0; mt < 4; mt++)
#pragma unroll
        for (int nt = 0; nt < 4; nt++)
          acc[mt][nt] = __builtin_amdgcn_mfma_f32_16x16x32_bf16(
              af[mt], bfr[nt], acc[mt][nt], 0, 0, 0);
    }
  }

  __syncthreads();
  int gc0 = col0 + nbase;
#pragma unroll
  for (int nt = 0; nt < 4; nt++) {
    int colt = wn * 64 + nt * 16 + l16;
    int gcol = gc0 + colt;
    int seg = gcol >> 8;
    int ci = gcol & 255;
    float bvv = (seg == 0) ? bq[ci] : (seg == 1) ? bk[ci] : bv[ci];
    const float* mask = (seg == 0) ? mq : mkv;
    bool doelu = seg < 2;
#pragma unroll
    for (int mt = 0; mt < 4; mt++) {
      int rowt0 = wm * 64 + mt * 16 + quad * 4;
#pragma unroll
      for (int r = 0; r < 4; r++) {
        int rowt = rowt0 + r;
        float v = acc[mt][nt][r] + bvv;
        if (doelu) v = v > 0.f ? v + 1.f : __expf(v);
        v *= mask[mbase + rowt];
        Cs[rowt][colt] = f2b(v);
      }
    }
  }
  __syncthreads();
#pragma unroll
  for (int it = 0; it < 8; it++) {
    int idx = tid + it * 256;
    int row = idx >> 4, c = idx & 15;
    uint4 v = *(const uint4*)&Cs[row][c * 8];
    *(uint4*)(C + (mbase + row) * (long)QKV_LD + gc0 + c * 8) = v;
  }
}

// ---------------------------------------------------------------------------
// FUSED TAIL v2b: M = LN(Ab@WmT + bm) ; H1 = relu(M@w1T) ; O = H1@w2T ;
// out = LN(O)*g2+b2 + residual (fp32), Xb = bf16 mirror.
// 512 thr (8 waves), 64 rows/block. Weight B-fragments are PER-WAVE-EXCLUSIVE
// -> loaded directly global->VGPR (L2-hot), no staging barriers.
// v2b: NO min-waves clamp (R5's (512,4) forced VGPR=64 -> acc spills ->
// 2.3x HBM traffic). accT reused for phase A and phase B accumulation
// (dead after LN1) to keep VGPR <=128 (2 blocks/CU at 70 KB LDS).
// ---------------------------------------------------------------------------
__global__ __launch_bounds__(512) void tail_fused(
    const __hip_bfloat16* __restrict__ A, const __hip_bfloat16* __restrict__ WmT,
    const __hip_bfloat16* __restrict__ w1T, const __hip_bfloat16* __restrict__ w2T,
    const float* __restrict__ bm,
    const float* __restrict__ g1, const float* __restrict__ b1,
    const float* __restrict__ g2, const float* __restrict__ b2,
    float* __restrict__ outF, __hip_bfloat16* __restrict__ Xb) {
  __shared__ alignas(16) char smem[70144];
  ushort* AsH = (ushort*)smem;             // phase A: As[64][256]; later H1u
  ushort* Msu = (ushort*)(smem + 32768);   // M [64][256] swizzled; later Xsu
  float* pS  = (float*)(smem + 65536);     // [8][64]
  float* pS2 = (float*)(smem + 67584);     // [8][64]
  float* muA = (float*)(smem + 69632);     // [64]
  float* rsA = (float*)(smem + 69888);     // [64]

  int tid = threadIdx.x;
  int wave = tid >> 6, lane = tid & 63;
  int quad = lane >> 4, l16 = lane & 15;
  long mbase = (long)blockIdx.x * 64;
  int cx = l16 & 7;            // == (fragment row)&7 for rows mt*16+l16
  int rswL = cx * 8;           // Msu/H1u column XOR for this lane's rows

  // accT: phase A accumulator, then reused as phase B accumulator.
  // accC: persistent w2 accumulator (across both halves).
  f32x4 accT[4][2], accC[4][2];
#pragma unroll
  for (int i = 0; i < 4; i++)
#pragma unroll
    for (int j = 0; j < 2; j++) {
      accT[i][j] = (f32x4){0.f, 0.f, 0.f, 0.f};
      accC[i][j] = (f32x4){0.f, 0.f, 0.f, 0.f};
    }

  // ---- stage full A-panel 64x256 (chunk-swizzled: LDS[r][j]=glob[r][j^(r&7)])
  {
    int r2 = lane >> 5;          // row within pair
    int c32 = lane & 31;         // chunk within row
#pragma unroll
    for (int j = 0; j < 4; j++) {
      int r0 = wave * 8 + j * 2;
      int r = r0 + r2;
      gll16(A + (mbase + r) * 256 + ((c32 ^ (r & 7)) * 8),
            (char*)AsH + r0 * 512);
    }
  }
  __syncthreads();   // drains vmcnt before barrier (HIP semantics)

  // ---- phase A: accT = Ab @ WmT (B-frags direct from global) ----
#pragma unroll
  for (int ks = 0; ks < 256; ks += 32) {
    short8 af[4], bfr[2];
#pragma unroll
    for (int nt = 0; nt < 2; nt++) {
      int n = wave * 32 + nt * 16 + l16;
      bfr[nt] = *(const short8*)&WmT[n * 256 + ks + quad * 8];
    }
    int ch = ((ks >> 3) + quad) ^ cx;
#pragma unroll
    for (int mt = 0; mt < 4; mt++)
      af[mt] = *(const short8*)&AsH[(mt * 16 + l16) * 256 + ch * 8];
#pragma unroll
    for (int mt = 0; mt < 4; mt++)
#pragma unroll
      for (int nt = 0; nt < 2; nt++)
        accT[mt][nt] = __builtin_amdgcn_mfma_f32_16x16x32_bf16(
            af[mt], bfr[nt], accT[mt][nt], 0, 0, 0);
  }

  // ---- LN1 -> Msu ----
  float br[2], gr[2], blr[2];
#pragma unroll
  for (int nt = 0; nt < 2; nt++) {
    int gcol = wave * 32 + nt * 16 + l16;
    br[nt] = bm[gcol];
    gr[nt] = g1[gcol];
    blr[nt] = b1[gcol];
  }
#pragma unroll
  for (int mt = 0; mt < 4; mt++)
#pragma unroll
    for (int r = 0; r < 4; r++) {
      float s = 0.f, s2 = 0.f;
#pragma unroll
      for (int nt = 0; nt < 2; nt++) {
        float v = accT[mt][nt][r] + br[nt];
        s += v;
        s2 += v * v;
      }
      s += __shfl_xor(s, 1);  s2 += __shfl_xor(s2, 1);
      s += __shfl_xor(s, 2);  s2 += __shfl_xor(s2, 2);
      s += __shfl_xor(s, 4);  s2 += __shfl_xor(s2, 4);
      s += __shfl_xor(s, 8);  s2 += __shfl_xor(s2, 8);
      if (l16 == 0) {
        int row = mt * 16 + quad * 4 + r;
        pS[wave * 64 + row] = s;
        pS2[wave * 64 + row] = s2;
      }
    }
  __syncthreads();
  if (tid < 64) {
    float S = 0.f, S2 = 0.f;
#pragma unroll
    for (int w = 0; w < 8; w++) { S += pS[w * 64 + tid]; S2 += pS2[w * 64 + tid]; }
    float mu = S * (1.f / 256.f);
    float var = S2 * (1.f / 256.f) - mu * mu;
    muA[tid] = mu;
    rsA[tid] = rsqrtf(var + 1e-5f);
  }
  __syncthreads();
#pragma unroll
  for (int mt = 0; mt < 4; mt++)
#pragma unroll
    for (int r = 0; r < 4; r++) {
      int row = mt * 16 + quad * 4 + r;
      float mu = muA[row], rs = rsA[row];
      int rsw = (row & 7) * 8;
#pragma unroll
      for (int nt = 0; nt < 2; nt++) {
        int col = wave * 32 + nt * 16 + l16;
        float v = accT[mt][nt][r] + br[nt];
        Msu[row * 256 + (col ^ rsw)] = f2b((v - mu) * rs * gr[nt] + blr[nt]);
      }
    }
  __syncthreads();   // Msu visible to all waves

  // ---- halves: B(half) -> H1 -> C(half), accC accumulates across halves ----
#pragma unroll
  for (int half = 0; half < 2; half++) {
    // phase B: accT (reused) = Ms @ w1T-half
#pragma unroll
    for (int i = 0; i < 4; i++)
#pragma unroll
      for (int j = 0; j < 2; j++) accT[i][j] = (f32x4){0.f, 0.f, 0.f, 0.f};
    const __hip_bfloat16* w1h = w1T + (size_t)half * 256 * 256;
#pragma unroll
    for (int ks = 0; ks < 256; ks += 32) {
      short8 af[4], bfr[2];
#pragma unroll
      for (int nt = 0; nt < 2; nt++) {
        int n = wave * 32 + nt * 16 + l16;
        bfr[nt] = *(const short8*)&w1h[n * 256 + ks + quad * 8];
      }
      int pcol = (ks + quad * 8) ^ rswL;
#pragma unroll
      for (int mt = 0; mt < 4; mt++)
        af[mt] = *(const short8*)&Msu[(mt * 16 + l16) * 256 + pcol];
#pragma unroll
      for (int mt = 0; mt < 4; mt++)
#pragma unroll
        for (int nt = 0; nt < 2; nt++)
          accT[mt][nt] = __builtin_amdgcn_mfma_f32_16x16x32_bf16(
              af[mt], bfr[nt], accT[mt][nt], 0, 0, 0);
    }
    __syncthreads();   // half0: phase-A AsH reads done; half1: C(half0) done
#pragma unroll
    for (int mt = 0; mt < 4; mt++)
#pragma unroll
      for (int r = 0; r < 4; r++) {
        int row = mt * 16 + quad * 4 + r;
        int rsw = (row & 7) * 8;
#pragma unroll
        for (int nt = 0; nt < 2; nt++) {
          int col = wave * 32 + nt * 16 + l16;
          float v = accT[mt][nt][r];
          AsH[row * 256 + (col ^ rsw)] = f2b(v > 0.f ? v : 0.f);
        }
      }
    __syncthreads();   // H1 visible
    // phase C: accC += H1 @ w2T-halfK
#pragma unroll
    for (int ks = 0; ks < 256; ks += 32) {
      short8 af[4], bfr[2];
#pragma unroll
      for (int nt = 0; nt < 2; nt++) {
        int n = wave * 32 + nt * 16 + l16;
        bfr[nt] = *(const short8*)&w2T[n * 512 + half * 256 + ks + quad * 8];
      }
      int pcol = (ks + quad * 8) ^ rswL;
#pragma unroll
      for (int mt = 0; mt < 4; mt++)
        af[mt] = *(const short8*)&AsH[(mt * 16 + l16) * 256 + pcol];
#pragma unroll
      for (int mt = 0; mt < 4; mt++)
#pragma unroll
        for (int nt = 0; nt < 2; nt++)
          accC[mt][nt] = __builtin_amdgcn_mfma_f32_16x16x32_bf16(
              af[mt], bfr[nt], accC[mt][nt], 0, 0, 0);
    }
  }

  // ---- LN2 + residual + Xb ----
  float g2r[2], b2r[2];
#pragma unroll
  for (int nt = 0; nt < 2; nt++) {
    int gcol = wave * 32 + nt * 16 + l16;
    g2r[nt] = g2[gcol];
    b2r[nt] = b2[gcol];
  }
#pragma unroll
  for (int mt = 0; mt < 4; mt++)
#pragma unroll
    for (int r = 0; r < 4; r++) {
      float s = 0.f, s2 = 0.f;
#pragma unroll
      for (int nt = 0; nt < 2; nt++) {
        float v = accC[mt][nt][r];
        s += v;
        s2 += v * v;
      }
      s += __shfl_xor(s, 1);  s2 += __shfl_xor(s2, 1);
      s += __shfl_xor(s, 2);  s2 += __shfl_xor(s2, 2);
      s += __shfl_xor(s, 4);  s2 += __shfl_xor(s2, 4);
      s += __shfl_xor(s, 8);  s2 += __shfl_xor(s2, 8);
      if (l16 == 0) {
        int row = mt * 16 + quad * 4 + r;
        pS[wave * 64 + row] = s;
        pS2[wave * 64 + row] = s2;
      }
    }
  __syncthreads();
  if (tid < 64) {
    float S = 0.f, S2 = 0.f;
#pragma unroll
    for (int w = 0; w < 8; w++) { S += pS[w * 64 + tid]; S2 += pS2[w * 64 + tid]; }
    float mu = S * (1.f / 256.f);
    float var = S2 * (1.f / 256.f) - mu * mu;
    muA[tid] = mu;
    rsA[tid] = rsqrtf(var + 1e-5f);
  }
  __syncthreads();
  ushort* Xsu = Msu;   // Msu dead (last read: B half1) -> Xb staging
#pragma unroll
  for (int mt = 0; mt < 4; mt++)
#pragma unroll
    for (int r = 0; r < 4; r++) {
      int row = mt * 16 + quad * 4 + r;
      float mu = muA[row], rs = rsA[row];
      int qx = quad * 8;    // ((row>>2)&3)*8 == quad*8 here
#pragma unroll
      for (int nt = 0; nt < 2; nt++) {
        int gcol = wave * 32 + nt * 16 + l16;
        float ln = (accC[mt][nt][r] - mu) * rs * g2r[nt] + b2r[nt];
        float* op = outF + (mbase + row) * 256 + gcol;
        float rr = *op + ln;          // residual in fp32
        *op = rr;
        Xsu[row * 256 + (gcol ^ qx)] = f2b(rr);
      }
    }
  __syncthreads();
#pragma unroll
  for (int it = 0; it < 4; it++) {
    int idx = tid + it * 512;        // 0..2047 -> 64 rows x 32 chunks
    int row = idx >> 5, c = idx & 31;
    int pc = c ^ ((row >> 2) & 3);   // undo quad-XOR swizzle
    uint4 v = *(const uint4*)&Xsu[row * 256 + pc * 8];
    *(uint4*)(Xb + (mbase + row) * 256L + c * 8) = v;
  }
}

// ---------------------------------------------------------------------------
// KV reduce from QKV buffer (stride 768; K at +256, V at +512).
// ---------------------------------------------------------------------------
__global__ __launch_bounds__(256) void kv_reduce(
    const __hip_bfloat16* __restrict__ QKV, float* __restrict__ KV,
    float* __restrict__ Ksum) {
  int b = blockIdx.x, h = blockIdx.y, c = blockIdx.z;
  __shared__ float Kl[32][40], Vl[32][40];
  int t = threadIdx.x;
  int lrow = t >> 3, le = (t & 7) * 4;
  int d = t >> 3, mg = t & 7;
  float a0 = 0.f, a1 = 0.f, a2 = 0.f, a3 = 0.f, ks = 0.f;
  int base = c * 480;
  for (int st = 0; st < 15; st++) {
    int s0 = base + st * 32;
    __syncthreads();
    {
      long n = (long)b * LSEQ + s0 + lrow;
      ushort4 ku = *(const ushort4*)(QKV + n * QKV_LD + 256 + h * 32 + le);
      ushort4 vu = *(const ushort4*)(QKV + n * QKV_LD + 512 + h * 32 + le);
      float4 kf = {b2f(ku.x), b2f(ku.y), b2f(ku.z), b2f(ku.w)};
      float4 vf = {b2f(vu.x), b2f(vu.y), b2f(vu.z), b2f(vu.w)};
      *(float4*)&Kl[lrow][le] = kf;
      *(float4*)&Vl[lrow][le] = vf;
    }
    __syncthreads();
#pragma unroll
    for (int ss = 0; ss < 32; ss++) {
      float kd = Kl[ss][d];
      float4 v4 = *(const float4*)&Vl[ss][mg * 4];
      a0 += kd * v4.x; a1 += kd * v4.y; a2 += kd * v4.z; a3 += kd * v4.w;
      if (mg == 0) ks += kd;
    }
  }
  int bh = b * 8 + h;
  float* p = KV + ((long)bh * 32 + d) * 32 + mg * 4;
  atomicAdd(&p[0], a0); atomicAdd(&p[1], a1);
  atomicAdd(&p[2], a2); atomicAdd(&p[3], a3);
  if (mg == 0) atomicAdd(&Ksum[bh * 32 + d], ks);
}

// ---------------------------------------------------------------------------
// Attention output from QKV buffer (Q stride 768); writes O (stride 256).
// ---------------------------------------------------------------------------
__global__ __launch_bounds__(256) void attn_out(
    const __hip_bfloat16* __restrict__ QKV, const float* __restrict__ KV,
    const float* __restrict__ Ksum, __hip_bfloat16* __restrict__ O) {
  int b = blockIdx.y, h = blockIdx.z;
  int bh = b * 8 + h;
  __shared__ float KVl[32][36];
  int t = threadIdx.x;
  for (int i = t; i < 1024; i += 256) KVl[i >> 5][i & 31] = KV[((long)bh << 10) + i];
  int lane = t & 63, wave = t >> 6;
  int cg = lane & 7, rs = lane >> 3;
  float4 ksr = *(const float4*)&Ksum[bh * 32 + cg * 4];
  __syncthreads();

  int rowEnd = blockIdx.x * 192 + 192;
  for (int r = blockIdx.x * 192 + wave * 8 + rs; r < rowEnd; r += 32) {
    long n = (long)b * LSEQ + r;
    ushort4 qu = *(const ushort4*)(QKV + n * QKV_LD + h * 32 + cg * 4);
    float q0 = b2f(qu.x), q1 = b2f(qu.y), q2 = b2f(qu.z), q3 = b2f(qu.w);
    float den = q0 * ksr.x + q1 * ksr.y + q2 * ksr.z + q3 * ksr.w;
    den += __shfl_xor(den, 1);
    den += __shfl_xor(den, 2);
    den += __shfl_xor(den, 4);
    float s0 = 0.f, s1 = 0.f, s2 = 0.f, s3 = 0.f;
    int gbase = lane & ~7;
#pragma unroll
    for (int j = 0; j < 8; j++) {
      int src = gbase | j;
      float qa = __shfl(q0, src);
      float qb = __shfl(q1, src);
      float qc = __shfl(q2, src);
      float qd = __shfl(q3, src);
      float4 k0 = *(const float4*)&KVl[j * 4 + 0][cg * 4];
      float4 k1 = *(const float4*)&KVl[j * 4 + 1][cg * 4];
      float4 k2 = *(const float4*)&KVl[j * 4 + 2][cg * 4];
      float4 k3 = *(const float4*)&KVl[j * 4 + 3][cg * 4];
      s0 += qa * k0.x + qb * k1.x + qc * k2.x + qd * k3.x;
      s1 += qa * k0.y + qb * k1.y + qc * k2.y + qd * k3.y;
      s2 += qa * k0.z + qb * k1.z + qc * k2.z + qd * k3.z;
      s3 += qa * k0.w + qb * k1.w + qc * k2.w + qd * k3.w;
    }
    float inv = 1.0f / (den + 1e-6f);
    ushort4 ou = {f2b(s0 * inv), f2b(s1 * inv), f2b(s2 * inv), f2b(s3 * inv)};
    *(ushort4*)(O + n * 256 + h * 32 + cg * 4) = ou;
  }
}

// ---------------------------------------------------------------------------
extern "C" void kernel_launch(void* const* d_in, const int* in_sizes, int n_in,
                              void* d_out, int out_size, void* d_ws, size_t ws_size,
                              hipStream_t stream) {
  const float* desc0 = (const float*)d_in[0];
  const float* desc1 = (const float*)d_in[1];
  const float* mask0 = (const float*)d_in[2];
  const float* mask1 = (const float*)d_in[3];
  const float* Wq = (const float*)d_in[4];
  const float* bq = (const float*)d_in[5];
  const float* Wk = (const float*)d_in[6];
  const float* bk = (const float*)d_in[7];
  const float* Wv = (const float*)d_in[8];
  const float* bv = (const float*)d_in[9];
  const float* Wm = (const float*)d_in[10];
  const float* bm = (const float*)d_in[11];
  const float* w1 = (const float*)d_in[12];
  const float* w2 = (const float*)d_in[13];
  const float* g1 = (const float*)d_in[14];
  const float* b1 = (const float*)d_in[15];
  const float* g2 = (const float*)d_in[16];
  const float* b2 = (const float*)d_in[17];

  char* ws = (char*)d_ws;
  size_t used = 0;
  auto alloc = [&](size_t bytes) {
    char* p = ws + used;
    used += (bytes + 255) & ~(size_t)255;
    return p;
  };
  __hip_bfloat16* WqkvT = (__hip_bfloat16*)alloc((size_t)768 * 256 * 2);
  __hip_bfloat16* WmT = (__hip_bfloat16*)alloc(256 * 256 * 2);
  __hip_bfloat16* w1T = (__hip_bfloat16*)alloc((size_t)8 * 512 * 256 * 2);
  __hip_bfloat16* w2T = (__hip_bfloat16*)alloc((size_t)8 * 256 * 512 * 2);
  // X0b and X1b MUST stay adjacent: the merged path treats them as one
  // [2*NROWS,256] matrix.
  __hip_bfloat16* X0b = (__hip_bfloat16*)alloc((size_t)NROWS * 256 * 2);
  __hip_bfloat16* X1b = (__hip_bfloat16*)alloc((size_t)NROWS * 256 * 2);
  __hip_bfloat16* QKV = (__hip_bfloat16*)alloc((size_t)NROWS * QKV_LD * 2);
  __hip_bfloat16* Ab2 = (__hip_bfloat16*)alloc((size_t)2 * NROWS * 256 * 2);
  float* KVws = (float*)alloc((64 * 1024 + 64 * 32) * 4);
  float* Ksum = KVws + 64 * 1024;
  bool merged = used <= ws_size;

  // weight prep
  transpose_bf16<<<dim3(8, 8, 1), 256, 0, stream>>>(Wq, WqkvT, 256, 256);
  transpose_bf16<<<dim3(8, 8, 1), 256, 0, stream>>>(Wk, WqkvT + 65536, 256, 256);
  transpose_bf16<<<dim3(8, 8, 1), 256, 0, stream>>>(Wv, WqkvT + 131072, 256, 256);
  transpose_bf16<<<dim3(8, 8, 1), 256, 0, stream>>>(Wm, WmT, 256, 256);
  transpose_bf16<<<dim3(16, 8, 8), 256, 0, stream>>>(w1, w1T, 256, 512);
  transpose_bf16<<<dim3(8, 16, 8), 256, 0, stream>>>(w2, w2T, 512, 256);

  long nElem = (long)NROWS * 256;
  long n4 = nElem / 4;
  init_x<<<(n4 + 255) / 256, 256, 0, stream>>>(desc0, desc1, (float*)d_out,
                                               X0b, X1b, n4);

  // QKV projection + linear attention for one stream; output rows at Oout.
  auto attn_stage = [&](const __hip_bfloat16* Xq, const __hip_bfloat16* Xkv,
                        const float* mq, const float* ms,
                        __hip_bfloat16* Oout, bool self) {
    if (self) {
      gemm_qkv<<<dim3(6, 300), 256, 0, stream>>>(Xq, WqkvT, QKV, 0,
                                                 bq, bk, bv, mq, ms);
    } else {
      gemm_qkv<<<dim3(2, 300), 256, 0, stream>>>(Xq, WqkvT, QKV, 0,
                                                 bq, bk, bv, mq, ms);
      gemm_qkv<<<dim3(4, 300), 256, 0, stream>>>(Xkv, WqkvT + 65536, QKV, 256,
                                                 bq, bk, bv, mq, ms);
    }
    hipMemsetAsync(KVws, 0, (64 * 1024 + 64 * 32) * 4, stream);
    kv_reduce<<<dim3(BATCH, NHEAD, 10), 256, 0, stream>>>(QKV, KVws, Ksum);
    attn_out<<<dim3(25, BATCH, NHEAD), 256, 0, stream>>>(QKV, KVws, Ksum, Oout);
  };

  auto tail = [&](int nblk, int i, float* oF, __hip_bfloat16* Xb) {
    tail_fused<<<nblk, 512, 0, stream>>>(
        Ab2, WmT, w1T + (size_t)i * 512 * 256, w2T + (size_t)i * 256 * 512,
        bm, g1 + i * 256, b1 + i * 256, g2 + i * 256, b2 + i * 256, oF, Xb);
  };

  // Merged self pair: both streams' tails in one double-M launch.
  auto self_pair = [&](int i) {
    attn_stage(X0b, X0b, mask0, mask0, Ab2, true);
    attn_stage(X1b, X1b, mask1, mask1, Ab2 + nElem, true);
    tail(2 * NROWS / 64, i, (float*)d_out, X0b);
  };

  // Single-stream layer (cross layers, and fallback for self).
  auto layer_one = [&](int x, int s, int i) {
    __hip_bfloat16* Xx = x ? X1b : X0b;
    __hip_bfloat16* Xs = s ? X1b : X0b;
    const float* mx = x ? mask1 : mask0;
    const float* ms = s ? mask1 : mask0;
    attn_stage(Xx, Xs, mx, ms, Ab2, x == s);
    tail(NROWS / 64, i, (float*)d_out + (size_t)x * nElem, Xx);
  };

  for (int i = 0; i < 8; i++) {
    if (i % 2 == 0) {        // self: independent streams -> merge tails
      if (merged) {
        self_pair(i);
      } else {
        layer_one(0, 0, i);
        layer_one(1, 1, i);
      }
    } else {                 // cross (desc1 sees UPDATED desc0) -> sequential
      layer_one(0, 1, i);
      layer_one(1, 0, i);
    }
  }
}

// Round 7
// 2970.385 us; speedup vs baseline: 1.2457x; 1.1367x over previous
//
#include <hip/hip_runtime.h>
#include <hip/hip_bf16.h>

typedef __attribute__((ext_vector_type(8))) short short8;
typedef __attribute__((ext_vector_type(4))) float f32x4;

#define NROWS 38400      // B*L = 8*4800
#define LSEQ 4800
#define BATCH 8
#define NHEAD 8
#define QKV_LD 768

__device__ inline float b2f(ushort u) {
  union { ushort s; __hip_bfloat16 h; } c;
  c.s = u;
  return __bfloat162float(c.h);
}
__device__ inline ushort f2b(float f) {
  union { ushort s; __hip_bfloat16 h; } c;
  c.h = __float2bfloat16(f);
  return c.s;
}

// async global->LDS, 16B per lane. LDS dst = wave-uniform base + lane*16.
__device__ inline void gll16(const void* g, void* l) {
  __builtin_amdgcn_global_load_lds(
      (const __attribute__((address_space(1))) void*)g,
      (__attribute__((address_space(3))) void*)l, 16, 0, 0);
}

// ---------------------------------------------------------------------------
// Tiled transpose + fp32->bf16: dst[c][r] = src[r][c], batched over blockIdx.z.
// ---------------------------------------------------------------------------
__global__ __launch_bounds__(256) void transpose_bf16(
    const float* __restrict__ src, __hip_bfloat16* __restrict__ dst, int R, int C) {
  src += (size_t)blockIdx.z * R * C;
  dst += (size_t)blockIdx.z * R * C;
  __shared__ float tile[32][33];
  int bx = blockIdx.x, by = blockIdx.y;
  int tx = threadIdx.x & 31, ty = threadIdx.x >> 5;
  for (int rr = ty; rr < 32; rr += 8)
    tile[rr][tx] = src[(long)(by * 32 + rr) * C + bx * 32 + tx];
  __syncthreads();
  for (int rr = ty; rr < 32; rr += 8)
    dst[(long)(bx * 32 + rr) * R + by * 32 + tx] = __float2bfloat16(tile[tx][rr]);
}

// ---------------------------------------------------------------------------
// Init (float4-vectorized): residual stream + bf16 mirrors.
// ---------------------------------------------------------------------------
__global__ __launch_bounds__(256) void init_x(
    const float* __restrict__ d0, const float* __restrict__ d1,
    float* __restrict__ outF, __hip_bfloat16* __restrict__ X0b,
    __hip_bfloat16* __restrict__ X1b, long n4) {
  long i = (long)blockIdx.x * 256 + threadIdx.x;
  if (i < n4) {
    float4 a = ((const float4*)d0)[i];
    float4 b = ((const float4*)d1)[i];
    ((float4*)outF)[i] = a;
    ((float4*)outF)[n4 + i] = b;
    ushort4 ua = {f2b(a.x), f2b(a.y), f2b(a.z), f2b(a.w)};
    ushort4 ub = {f2b(b.x), f2b(b.y), f2b(b.z), f2b(b.w)};
    ((ushort4*)X0b)[i] = ua;
    ((ushort4*)X1b)[i] = ub;
  }
}

// ---------------------------------------------------------------------------
// Fused QKV projection GEMM. BM=128, BN=128, K=256, ldA=256, ldC=768.
// Supports merged two-stream M (grid.y up to 600): rows >= NROWS use the
// stream-1 masks. Each 128-row block lies entirely in one stream.
// ---------------------------------------------------------------------------
__global__ __launch_bounds__(256) void gemm_qkv(
    const __hip_bfloat16* __restrict__ A, const __hip_bfloat16* __restrict__ Bt,
    __hip_bfloat16* __restrict__ C, int col0,
    const float* __restrict__ bq, const float* __restrict__ bk,
    const float* __restrict__ bv,
    const float* __restrict__ mq0, const float* __restrict__ mkv0,
    const float* __restrict__ mq1, const float* __restrict__ mkv1) {
  __shared__ alignas(16) char smem[128 * 136 * 2];
  __hip_bfloat16 (*As)[64] = (__hip_bfloat16(*)[64])smem;
  __hip_bfloat16 (*Bs)[64] = (__hip_bfloat16(*)[64])(smem + 128 * 64 * 2);
  ushort (*Cs)[136] = (ushort(*)[136])smem;

  int tid = threadIdx.x;
  int wave = tid >> 6, lane = tid & 63;
  int wm = wave & 1, wn = wave >> 1;
  int quad = lane >> 4, l16 = lane & 15;
  long mbase = (long)blockIdx.y * 128;
  int nbase = blockIdx.x * 128;

  const float* mq = mq0;
  const float* mkv = mkv0;
  if (mbase >= NROWS) { mq = mq1 - NROWS; mkv = mkv1 - NROWS; }

  int srow = lane >> 3;
  int sck = (lane & 7) ^ srow;
  int cx = l16 & 7;

  f32x4 acc[4][4];
#pragma unroll
  for (int i = 0; i < 4; i++)
#pragma unroll
    for (int j = 0; j < 4; j++) acc[i][j] = (f32x4){0.f, 0.f, 0.f, 0.f};

  for (int kt = 0; kt < 256; kt += 64) {
    __syncthreads();
#pragma unroll
    for (int i = 0; i < 4; i++) {
      int r0 = wave * 32 + i * 8;
      gll16(A + (mbase + r0 + srow) * 256 + kt + sck * 8, &As[r0][0]);
      gll16(Bt + (long)(nbase + r0 + srow) * 256 + kt + sck * 8, &Bs[r0][0]);
    }
    __syncthreads();
#pragma unroll
    for (int ks = 0; ks < 64; ks += 32) {
      short8 af[4], bfr[4];
      int ch = ((ks >> 3) + quad) ^ cx;
#pragma unroll
      for (int mt = 0; mt < 4; mt++)
        af[mt] = *(const short8*)&As[wm * 64 + mt * 16 + l16][ch * 8];
#pragma unroll
      for (int nt = 0; nt < 4; nt++)
        bfr[nt] = *(const short8*)&Bs[wn * 64 + nt * 16 + l16][ch * 8];
#pragma unroll
      for (int mt = 0; mt < 4; mt++)
#pragma unroll
        for (int nt = 0; nt < 4; nt++)
          acc[mt][nt] = __builtin_amdgcn_mfma_f32_16x16x32_bf16(
              af[mt], bfr[nt], acc[mt][nt], 0, 0, 0);
    }
  }

  __syncthreads();
  int gc0 = col0 + nbase;
#pragma unroll
  for (int nt = 0; nt < 4; nt++) {
    int colt = wn * 64 + nt * 16 + l16;
    int gcol = gc0 + colt;
    int seg = gcol >> 8;
    int ci = gcol & 255;
    float bvv = (seg == 0) ? bq[ci] : (seg == 1) ? bk[ci] : bv[ci];
    const float* mask = (seg == 0) ? mq : mkv;
    bool doelu = seg < 2;
#pragma unroll
    for (int mt = 0; mt < 4; mt++) {
      int rowt0 = wm * 64 + mt * 16 + quad * 4;
#pragma unroll
      for (int r = 0; r < 4; r++) {
        int rowt = rowt0 + r;
        float v = acc[mt][nt][r] + bvv;
        if (doelu) v = v > 0.f ? v + 1.f : __expf(v);
        v *= mask[mbase + rowt];
        Cs[rowt][colt] = f2b(v);
      }
    }
  }
  __syncthreads();
#pragma unroll
  for (int it = 0; it < 8; it++) {
    int idx = tid + it * 256;
    int row = idx >> 4, c = idx & 15;
    uint4 v = *(const uint4*)&Cs[row][c * 8];
    *(uint4*)(C + (mbase + row) * (long)QKV_LD + gc0 + c * 8) = v;
  }
}

// ---------------------------------------------------------------------------
// FUSED TAIL (R4 pipelined version — measured 143us merged):
// M = LN(Ab@WmT + bm) ; H1 = relu(M@w1T) ; O = H1@w2T ;
// out = LN(O)*g2+b2 + residual (fp32), Xb = bf16 mirror.
// 512 thr (8 waves), 64 rows/block. M and H1 live in LDS only.
// Staging: 2x40960 dbuf (As 8K + Bs 32K), 2-deep pipeline with cross-phase
// tile-0 pre-issue. Ms/H1s chunk-XOR swizzled (phys = col ^ ((row&7)*8)).
// ---------------------------------------------------------------------------
__global__ __launch_bounds__(512) void tail_fused(
    const __hip_bfloat16* __restrict__ A, const __hip_bfloat16* __restrict__ WmT,
    const __hip_bfloat16* __restrict__ w1T, const __hip_bfloat16* __restrict__ w2T,
    const float* __restrict__ bm,
    const float* __restrict__ g1, const float* __restrict__ b1,
    const float* __restrict__ g2, const float* __restrict__ b2,
    float* __restrict__ outF, __hip_bfloat16* __restrict__ Xb) {
  __shared__ alignas(16) char smem[152064];
  // [0, 81920): 2 staging bufs x 40960 (As[64][64] @ +0, Bs[256][64] @ +8192)
  ushort* Msu  = (ushort*)(smem + 81920);    // M   [64][256] swizzled
  ushort* H1u  = (ushort*)(smem + 114688);   // H1  [64][256] swizzled (per half)
  float* pS  = (float*)(smem + 147456);      // [8][64]
  float* pS2 = (float*)(smem + 149504);      // [8][64]
  float* muA = (float*)(smem + 151552);      // [64]
  float* rsA = (float*)(smem + 151808);      // [64]

  int tid = threadIdx.x;
  int wave = tid >> 6, lane = tid & 63;
  int quad = lane >> 4, l16 = lane & 15;
  long mbase = (long)blockIdx.x * 64;
  int srow = lane >> 3;
  int sck = (lane & 7) ^ srow;
  int cx = l16 & 7;
  int swz = cx * 8;

  f32x4 accA[4][2], accB[4][2], accC[4][2];
#pragma unroll
  for (int i = 0; i < 4; i++)
#pragma unroll
    for (int j = 0; j < 2; j++) {
      accA[i][j] = (f32x4){0.f, 0.f, 0.f, 0.f};
      accC[i][j] = (f32x4){0.f, 0.f, 0.f, 0.f};
    }

  auto stageA = [&](int b, int kt) {
    char* base = smem + b * 40960;
    __hip_bfloat16 (*As)[64] = (__hip_bfloat16(*)[64])base;
    __hip_bfloat16 (*Bs)[64] = (__hip_bfloat16(*)[64])(base + 8192);
    gll16(A + (mbase + wave * 8 + srow) * 256 + kt + sck * 8, &As[wave * 8][0]);
#pragma unroll
    for (int j = 0; j < 4; j++) {
      int r0 = wave * 32 + j * 8;
      gll16(WmT + (r0 + srow) * 256 + kt + sck * 8, &Bs[r0][0]);
    }
  };
  auto stageB = [&](int b, int half, int kt) {
    __hip_bfloat16 (*Bs)[64] = (__hip_bfloat16(*)[64])(smem + b * 40960 + 8192);
#pragma unroll
    for (int j = 0; j < 4; j++) {
      int r0 = wave * 32 + j * 8;
      gll16(w1T + (half * 256 + r0 + srow) * 256 + kt + sck * 8, &Bs[r0][0]);
    }
  };
  auto stageC = [&](int b, int half, int kt) {
    __hip_bfloat16 (*Bs)[64] = (__hip_bfloat16(*)[64])(smem + b * 40960 + 8192);
#pragma unroll
    for (int j = 0; j < 4; j++) {
      int r0 = wave * 32 + j * 8;
      gll16(w2T + (r0 + srow) * 512L + half * 256 + kt + sck * 8, &Bs[r0][0]);
    }
  };

  auto computeA = [&](int b) {
    char* base = smem + b * 40960;
    __hip_bfloat16 (*As)[64] = (__hip_bfloat16(*)[64])base;
    __hip_bfloat16 (*Bs)[64] = (__hip_bfloat16(*)[64])(base + 8192);
#pragma unroll
    for (int ks = 0; ks < 64; ks += 32) {
      short8 af[4], bfr[2];
      int ch = ((ks >> 3) + quad) ^ cx;
#pragma unroll
      for (int mt = 0; mt < 4; mt++)
        af[mt] = *(const short8*)&As[mt * 16 + l16][ch * 8];
#pragma unroll
      for (int nt = 0; nt < 2; nt++)
        bfr[nt] = *(const short8*)&Bs[wave * 32 + nt * 16 + l16][ch * 8];
#pragma unroll
      for (int mt = 0; mt < 4; mt++)
#pragma unroll
        for (int nt = 0; nt < 2; nt++)
          accA[mt][nt] = __builtin_amdgcn_mfma_f32_16x16x32_bf16(
              af[mt], bfr[nt], accA[mt][nt], 0, 0, 0);
    }
  };
  auto computeB = [&](int b, int kt) {
    __hip_bfloat16 (*Bs)[64] = (__hip_bfloat16(*)[64])(smem + b * 40960 + 8192);
#pragma unroll
    for (int ks = 0; ks < 64; ks += 32) {
      short8 af[4], bfr[2];
      int ch = ((ks >> 3) + quad) ^ cx;
      int mcol = (kt + ks + quad * 8) ^ swz;
#pragma unroll
      for (int mt = 0; mt < 4; mt++)
        af[mt] = *(const short8*)&Msu[(mt * 16 + l16) * 256 + mcol];
#pragma unroll
      for (int nt = 0; nt < 2; nt++)
        bfr[nt] = *(const short8*)&Bs[wave * 32 + nt * 16 + l16][ch * 8];
#pragma unroll
      for (int mt = 0; mt < 4; mt++)
#pragma unroll
        for (int nt = 0; nt < 2; nt++)
          accB[mt][nt] = __builtin_amdgcn_mfma_f32_16x16x32_bf16(
              af[mt], bfr[nt], accB[mt][nt], 0, 0, 0);
    }
  };
  auto computeC = [&](int b, int kt) {
    __hip_bfloat16 (*Bs)[64] = (__hip_bfloat16(*)[64])(smem + b * 40960 + 8192);
#pragma unroll
    for (int ks = 0; ks < 64; ks += 32) {
      short8 af[4], bfr[2];
      int ch = ((ks >> 3) + quad) ^ cx;
      int hcol = (kt + ks + quad * 8) ^ swz;
#pragma unroll
      for (int mt = 0; mt < 4; mt++)
        af[mt] = *(const short8*)&H1u[(mt * 16 + l16) * 256 + hcol];
#pragma unroll
      for (int nt = 0; nt < 2; nt++)
        bfr[nt] = *(const short8*)&Bs[wave * 32 + nt * 16 + l16][ch * 8];
#pragma unroll
      for (int mt = 0; mt < 4; mt++)
#pragma unroll
        for (int nt = 0; nt < 2; nt++)
          accC[mt][nt] = __builtin_amdgcn_mfma_f32_16x16x32_bf16(
              af[mt], bfr[nt], accC[mt][nt], 0, 0, 0);
    }
  };

#define PIPE_SYNC                                      \
  asm volatile("s_waitcnt vmcnt(0)" ::: "memory");     \
  __builtin_amdgcn_sched_barrier(0);                   \
  __builtin_amdgcn_s_barrier();

  int cb = 0;
  stageA(0, 0);
  PIPE_SYNC
  // ---- phase A: M-acc = Ab @ WmT ----
#pragma unroll
  for (int t = 0; t < 4; t++) {
    if (t < 3) stageA(cb ^ 1, (t + 1) * 64); else stageB(cb ^ 1, 0, 0);
    computeA(cb);
    PIPE_SYNC
    cb ^= 1;
  }
  // ---- LN1 -> Ms (LDS only) ----
  float br[2], gr[2], blr[2];
#pragma unroll
  for (int nt = 0; nt < 2; nt++) {
    int gcol = wave * 32 + nt * 16 + l16;
    br[nt] = bm[gcol];
    gr[nt] = g1[gcol];
    blr[nt] = b1[gcol];
  }
#pragma unroll
  for (int mt = 0; mt < 4; mt++)
#pragma unroll
    for (int r = 0; r < 4; r++) {
      float s = 0.f, s2 = 0.f;
#pragma unroll
      for (int nt = 0; nt < 2; nt++) {
        float v = accA[mt][nt][r] + br[nt];
        s += v;
        s2 += v * v;
      }
      s += __shfl_xor(s, 1);  s2 += __shfl_xor(s2, 1);
      s += __shfl_xor(s, 2);  s2 += __shfl_xor(s2, 2);
      s += __shfl_xor(s, 4);  s2 += __shfl_xor(s2, 4);
      s += __shfl_xor(s, 8);  s2 += __shfl_xor(s2, 8);
      if (l16 == 0) {
        int row = mt * 16 + quad * 4 + r;
        pS[wave * 64 + row] = s;
        pS2[wave * 64 + row] = s2;
      }
    }
  __syncthreads();
  if (tid < 64) {
    float S = 0.f, S2 = 0.f;
#pragma unroll
    for (int w = 0; w < 8; w++) { S += pS[w * 64 + tid]; S2 += pS2[w * 64 + tid]; }
    float mu = S * (1.f / 256.f);
    float var = S2 * (1.f / 256.f) - mu * mu;
    muA[tid] = mu;
    rsA[tid] = rsqrtf(var + 1e-5f);
  }
  __syncthreads();
#pragma unroll
  for (int mt = 0; mt < 4; mt++)
#pragma unroll
    for (int r = 0; r < 4; r++) {
      int row = mt * 16 + quad * 4 + r;
      float mu = muA[row], rs = rsA[row];
      int rsw = (row & 7) * 8;
#pragma unroll
      for (int nt = 0; nt < 2; nt++) {
        int col = wave * 32 + nt * 16 + l16;
        float v = accA[mt][nt][r] + br[nt];
        Msu[row * 256 + (col ^ rsw)] = f2b((v - mu) * rs * gr[nt] + blr[nt]);
      }
    }
  __syncthreads();   // Ms visible to all waves; B1 tile0 already staged in cb

  // ---- halves: B1,C1,B2,C2 ----
#pragma unroll
  for (int half = 0; half < 2; half++) {
    // phase B: accB = Ms @ w1T-half
    f32x4 accB_init;
#pragma unroll
    for (int i = 0; i < 4; i++)
#pragma unroll
      for (int j = 0; j < 2; j++) accB[i][j] = (f32x4){0.f, 0.f, 0.f, 0.f};
    (void)accB_init;
#pragma unroll
    for (int t = 0; t < 4; t++) {
      if (t < 3) stageB(cb ^ 1, half, (t + 1) * 64); else stageC(cb ^ 1, half, 0);
      computeB(cb, t * 64);
      PIPE_SYNC
      cb ^= 1;
    }
    // H1s = relu(accB)
#pragma unroll
    for (int mt = 0; mt < 4; mt++)
#pragma unroll
      for (int r = 0; r < 4; r++) {
        int row = mt * 16 + quad * 4 + r;
        int rsw = (row & 7) * 8;
#pragma unroll
        for (int nt = 0; nt < 2; nt++) {
          int col = wave * 32 + nt * 16 + l16;
          float v = accB[mt][nt][r];
          H1u[row * 256 + (col ^ rsw)] = f2b(v > 0.f ? v : 0.f);
        }
      }
    __syncthreads();
    // phase C: accC += H1s @ w2T-halfK
#pragma unroll
    for (int t = 0; t < 4; t++) {
      if (t < 3) stageC(cb ^ 1, half, (t + 1) * 64);
      else if (half == 0) stageB(cb ^ 1, 1, 0);
      computeC(cb, t * 64);
      PIPE_SYNC
      cb ^= 1;
    }
  }

  // ---- LN2 + residual + Xb ----
  float g2r[2], b2r[2];
#pragma unroll
  for (int nt = 0; nt < 2; nt++) {
    int gcol = wave * 32 + nt * 16 + l16;
    g2r[nt] = g2[gcol];
    b2r[nt] = b2[gcol];
  }
#pragma unroll
  for (int mt = 0; mt < 4; mt++)
#pragma unroll
    for (int r = 0; r < 4; r++) {
      float s = 0.f, s2 = 0.f;
#pragma unroll
      for (int nt = 0; nt < 2; nt++) {
        float v = accC[mt][nt][r];
        s += v;
        s2 += v * v;
      }
      s += __shfl_xor(s, 1);  s2 += __shfl_xor(s2, 1);
      s += __shfl_xor(s, 2);  s2 += __shfl_xor(s2, 2);
      s += __shfl_xor(s, 4);  s2 += __shfl_xor(s2, 4);
      s += __shfl_xor(s, 8);  s2 += __shfl_xor(s2, 8);
      if (l16 == 0) {
        int row = mt * 16 + quad * 4 + r;
        pS[wave * 64 + row] = s;
        pS2[wave * 64 + row] = s2;
      }
    }
  __syncthreads();
  if (tid < 64) {
    float S = 0.f, S2 = 0.f;
#pragma unroll
    for (int w = 0; w < 8; w++) { S += pS[w * 64 + tid]; S2 += pS2[w * 64 + tid]; }
    float mu = S * (1.f / 256.f);
    float var = S2 * (1.f / 256.f) - mu * mu;
    muA[tid] = mu;
    rsA[tid] = rsqrtf(var + 1e-5f);
  }
  __syncthreads();
  ushort* Xsu = Msu;   // Ms region dead -> reuse as Xb staging (unswizzled)
#pragma unroll
  for (int mt = 0; mt < 4; mt++)
#pragma unroll
    for (int r = 0; r < 4; r++) {
      int row = mt * 16 + quad * 4 + r;
      float mu = muA[row], rs = rsA[row];
#pragma unroll
      for (int nt = 0; nt < 2; nt++) {
        int gcol = wave * 32 + nt * 16 + l16;
        float ln = (accC[mt][nt][r] - mu) * rs * g2r[nt] + b2r[nt];
        float* op = outF + (mbase + row) * 256 + gcol;
        float rr = *op + ln;          // residual in fp32
        *op = rr;
        Xsu[row * 256 + gcol] = f2b(rr);
      }
    }
  __syncthreads();
#pragma unroll
  for (int it = 0; it < 4; it++) {
    int idx = tid + it * 512;        // 0..2047 -> 64 rows x 32 chunks
    int row = idx >> 5, c = idx & 31;
    uint4 v = *(const uint4*)&Xsu[row * 256 + c * 8];
    *(uint4*)(Xb + (mbase + row) * 256L + c * 8) = v;
  }
#undef PIPE_SYNC
}

// ---------------------------------------------------------------------------
// KV reduce from QKV buffer (stride 768; K at +256, V at +512).
// blockIdx.x (batch) may span 2 merged streams (up to 16).
// ---------------------------------------------------------------------------
__global__ __launch_bounds__(256) void kv_reduce(
    const __hip_bfloat16* __restrict__ QKV, float* __restrict__ KV,
    float* __restrict__ Ksum) {
  int b = blockIdx.x, h = blockIdx.y, c = blockIdx.z;
  __shared__ float Kl[32][40], Vl[32][40];
  int t = threadIdx.x;
  int lrow = t >> 3, le = (t & 7) * 4;
  int d = t >> 3, mg = t & 7;
  float a0 = 0.f, a1 = 0.f, a2 = 0.f, a3 = 0.f, ks = 0.f;
  int base = c * 480;
  for (int st = 0; st < 15; st++) {
    int s0 = base + st * 32;
    __syncthreads();
    {
      long n = (long)b * LSEQ + s0 + lrow;
      ushort4 ku = *(const ushort4*)(QKV + n * QKV_LD + 256 + h * 32 + le);
      ushort4 vu = *(const ushort4*)(QKV + n * QKV_LD + 512 + h * 32 + le);
      float4 kf = {b2f(ku.x), b2f(ku.y), b2f(ku.z), b2f(ku.w)};
      float4 vf = {b2f(vu.x), b2f(vu.y), b2f(vu.z), b2f(vu.w)};
      *(float4*)&Kl[lrow][le] = kf;
      *(float4*)&Vl[lrow][le] = vf;
    }
    __syncthreads();
#pragma unroll
    for (int ss = 0; ss < 32; ss++) {
      float kd = Kl[ss][d];
      float4 v4 = *(const float4*)&Vl[ss][mg * 4];
      a0 += kd * v4.x; a1 += kd * v4.y; a2 += kd * v4.z; a3 += kd * v4.w;
      if (mg == 0) ks += kd;
    }
  }
  int bh = b * 8 + h;
  float* p = KV + ((long)bh * 32 + d) * 32 + mg * 4;
  atomicAdd(&p[0], a0); atomicAdd(&p[1], a1);
  atomicAdd(&p[2], a2); atomicAdd(&p[3], a3);
  if (mg == 0) atomicAdd(&Ksum[bh * 32 + d], ks);
}

// ---------------------------------------------------------------------------
// Attention output from QKV buffer (Q stride 768); writes O (stride 256).
// blockIdx.y (batch) may span 2 merged streams (up to 16).
// ---------------------------------------------------------------------------
__global__ __launch_bounds__(256) void attn_out(
    const __hip_bfloat16* __restrict__ QKV, const float* __restrict__ KV,
    const float* __restrict__ Ksum, __hip_bfloat16* __restrict__ O) {
  int b = blockIdx.y, h = blockIdx.z;
  int bh = b * 8 + h;
  __shared__ float KVl[32][36];
  int t = threadIdx.x;
  for (int i = t; i < 1024; i += 256) KVl[i >> 5][i & 31] = KV[((long)bh << 10) + i];
  int lane = t & 63, wave = t >> 6;
  int cg = lane & 7, rs = lane >> 3;
  float4 ksr = *(const float4*)&Ksum[bh * 32 + cg * 4];
  __syncthreads();

  int rowEnd = blockIdx.x * 192 + 192;
  for (int r = blockIdx.x * 192 + wave * 8 + rs; r < rowEnd; r += 32) {
    long n = (long)b * LSEQ + r;
    ushort4 qu = *(const ushort4*)(QKV + n * QKV_LD + h * 32 + cg * 4);
    float q0 = b2f(qu.x), q1 = b2f(qu.y), q2 = b2f(qu.z), q3 = b2f(qu.w);
    float den = q0 * ksr.x + q1 * ksr.y + q2 * ksr.z + q3 * ksr.w;
    den += __shfl_xor(den, 1);
    den += __shfl_xor(den, 2);
    den += __shfl_xor(den, 4);
    float s0 = 0.f, s1 = 0.f, s2 = 0.f, s3 = 0.f;
    int gbase = lane & ~7;
#pragma unroll
    for (int j = 0; j < 8; j++) {
      int src = gbase | j;
      float qa = __shfl(q0, src);
      float qb = __shfl(q1, src);
      float qc = __shfl(q2, src);
      float qd = __shfl(q3, src);
      float4 k0 = *(const float4*)&KVl[j * 4 + 0][cg * 4];
      float4 k1 = *(const float4*)&KVl[j * 4 + 1][cg * 4];
      float4 k2 = *(const float4*)&KVl[j * 4 + 2][cg * 4];
      float4 k3 = *(const float4*)&KVl[j * 4 + 3][cg * 4];
      s0 += qa * k0.x + qb * k1.x + qc * k2.x + qd * k3.x;
      s1 += qa * k0.y + qb * k1.y + qc * k2.y + qd * k3.y;
      s2 += qa * k0.z + qb * k1.z + qc * k2.z + qd * k3.z;
      s3 += qa * k0.w + qb * k1.w + qc * k2.w + qd * k3.w;
    }
    float inv = 1.0f / (den + 1e-6f);
    ushort4 ou = {f2b(s0 * inv), f2b(s1 * inv), f2b(s2 * inv), f2b(s3 * inv)};
    *(ushort4*)(O + n * 256 + h * 32 + cg * 4) = ou;
  }
}

// ---------------------------------------------------------------------------
extern "C" void kernel_launch(void* const* d_in, const int* in_sizes, int n_in,
                              void* d_out, int out_size, void* d_ws, size_t ws_size,
                              hipStream_t stream) {
  const float* desc0 = (const float*)d_in[0];
  const float* desc1 = (const float*)d_in[1];
  const float* mask0 = (const float*)d_in[2];
  const float* mask1 = (const float*)d_in[3];
  const float* Wq = (const float*)d_in[4];
  const float* bq = (const float*)d_in[5];
  const float* Wk = (const float*)d_in[6];
  const float* bk = (const float*)d_in[7];
  const float* Wv = (const float*)d_in[8];
  const float* bv = (const float*)d_in[9];
  const float* Wm = (const float*)d_in[10];
  const float* bm = (const float*)d_in[11];
  const float* w1 = (const float*)d_in[12];
  const float* w2 = (const float*)d_in[13];
  const float* g1 = (const float*)d_in[14];
  const float* b1 = (const float*)d_in[15];
  const float* g2 = (const float*)d_in[16];
  const float* b2 = (const float*)d_in[17];

  char* ws = (char*)d_ws;
  size_t used = 0;
  auto alloc = [&](size_t bytes) {
    char* p = ws + used;
    used += (bytes + 255) & ~(size_t)255;
    return p;
  };
  __hip_bfloat16* WqkvT = (__hip_bfloat16*)alloc((size_t)768 * 256 * 2);
  __hip_bfloat16* WmT = (__hip_bfloat16*)alloc(256 * 256 * 2);
  __hip_bfloat16* w1T = (__hip_bfloat16*)alloc((size_t)8 * 512 * 256 * 2);
  __hip_bfloat16* w2T = (__hip_bfloat16*)alloc((size_t)8 * 256 * 512 * 2);
  // X0b and X1b MUST stay adjacent: merged paths treat them as one
  // [2*NROWS,256] matrix (sizes are multiples of 256 B -> no padding gap).
  __hip_bfloat16* X0b = (__hip_bfloat16*)alloc((size_t)NROWS * 256 * 2);
  __hip_bfloat16* X1b = (__hip_bfloat16*)alloc((size_t)NROWS * 256 * 2);
  __hip_bfloat16* QKV = (__hip_bfloat16*)alloc((size_t)2 * NROWS * QKV_LD * 2);
  __hip_bfloat16* Ab2 = (__hip_bfloat16*)alloc((size_t)2 * NROWS * 256 * 2);
  float* KVws = (float*)alloc((128 * 1024 + 128 * 32) * 4);
  float* Ksum = KVws + 128 * 1024;
  bool merged = used <= ws_size;
  size_t kvBytes = (128 * 1024 + 128 * 32) * 4;

  // weight prep
  transpose_bf16<<<dim3(8, 8, 1), 256, 0, stream>>>(Wq, WqkvT, 256, 256);
  transpose_bf16<<<dim3(8, 8, 1), 256, 0, stream>>>(Wk, WqkvT + 65536, 256, 256);
  transpose_bf16<<<dim3(8, 8, 1), 256, 0, stream>>>(Wv, WqkvT + 131072, 256, 256);
  transpose_bf16<<<dim3(8, 8, 1), 256, 0, stream>>>(Wm, WmT, 256, 256);
  transpose_bf16<<<dim3(16, 8, 8), 256, 0, stream>>>(w1, w1T, 256, 512);
  transpose_bf16<<<dim3(8, 16, 8), 256, 0, stream>>>(w2, w2T, 512, 256);

  long nElem = (long)NROWS * 256;
  long n4 = nElem / 4;
  init_x<<<(n4 + 255) / 256, 256, 0, stream>>>(desc0, desc1, (float*)d_out,
                                               X0b, X1b, n4);

  auto tail = [&](int nblk, int i, float* oF, __hip_bfloat16* Xb) {
    tail_fused<<<nblk, 512, 0, stream>>>(
        Ab2, WmT, w1T + (size_t)i * 512 * 256, w2T + (size_t)i * 256 * 512,
        bm, g1 + i * 256, b1 + i * 256, g2 + i * 256, b2 + i * 256, oF, Xb);
  };

  // Merged self pair: one attention pass + one tail over both streams.
  auto self_pair = [&](int i) {
    gemm_qkv<<<dim3(6, 600), 256, 0, stream>>>(X0b, WqkvT, QKV, 0,
                                               bq, bk, bv,
                                               mask0, mask0, mask1, mask1);
    hipMemsetAsync(KVws, 0, kvBytes, stream);
    kv_reduce<<<dim3(16, NHEAD, 10), 256, 0, stream>>>(QKV, KVws, Ksum);
    attn_out<<<dim3(25, 16, NHEAD), 256, 0, stream>>>(QKV, KVws, Ksum, Ab2);
    tail(2 * NROWS / 64, i, (float*)d_out, X0b);
  };

  // Single-stream layer (cross layers, and fallback for self).
  auto layer_one = [&](int x, int s, int i) {
    __hip_bfloat16* Xx = x ? X1b : X0b;
    __hip_bfloat16* Xs = s ? X1b : X0b;
    const float* mx = x ? mask1 : mask0;
    const float* ms = s ? mask1 : mask0;
    if (x == s) {
      gemm_qkv<<<dim3(6, 300), 256, 0, stream>>>(Xx, WqkvT, QKV, 0,
                                                 bq, bk, bv, mx, ms, mx, ms);
    } else {
      gemm_qkv<<<dim3(2, 300), 256, 0, stream>>>(Xx, WqkvT, QKV, 0,
                                                 bq, bk, bv, mx, ms, mx, ms);
      gemm_qkv<<<dim3(4, 300), 256, 0, stream>>>(Xs, WqkvT + 65536, QKV, 256,
                                                 bq, bk, bv, mx, ms, mx, ms);
    }
    hipMemsetAsync(KVws, 0, kvBytes, stream);
    kv_reduce<<<dim3(BATCH, NHEAD, 10), 256, 0, stream>>>(QKV, KVws, Ksum);
    attn_out<<<dim3(25, BATCH, NHEAD), 256, 0, stream>>>(QKV, KVws, Ksum, Ab2);
    tail(NROWS / 64, i, (float*)d_out + (size_t)x * nElem, Xx);
  };

  for (int i = 0; i < 8; i++) {
    if (i % 2 == 0) {        // self: independent streams -> fully merged
      if (merged) {
        self_pair(i);
      } else {
        layer_one(0, 0, i);
        layer_one(1, 1, i);
      }
    } else {                 // cross (desc1 sees UPDATED desc0) -> sequential
      layer_one(0, 1, i);
      layer_one(1, 0, i);
    }
  }
}